// Round 2
// baseline (524.072 us; speedup 1.0000x reference)
//
#include <hip/hip_runtime.h>

#define DM    1024
#define NB    4
#define SEQ   2048
#define SOUT  2049
#define TPAD  2176                 // 17*128 padded t-rows per batch
#define PREF  32                   // zero prefix rows per batch (max shift 16)
#define ROWB  (PREF + TPAD)        // 2208 physical rows per batch
#define ZROWS (NB * ROWB)          // 8832
#define RTPB  (TPAD / 128)         // 17 row tiles per batch
#define NKS   (DM / 64)            // 16 K-steps of BK=64

typedef __attribute__((ext_vector_type(8))) short  short8;   // 8 x bf16
typedef __attribute__((ext_vector_type(4))) float  f32x4;
typedef unsigned long long ull;
typedef unsigned short u16;

__device__ __forceinline__ u16 f2bf(float f) {
    unsigned u = __builtin_bit_cast(unsigned, f);
    u += 0x7fffu + ((u >> 16) & 1u);          // RNE
    return (u16)(u >> 16);
}
__device__ __forceinline__ float bf2f(u16 h) {
    return __builtin_bit_cast(float, (unsigned)h << 16);
}
__device__ __forceinline__ ull pack4(float a, float b, float c, float d) {
    return (ull)f2bf(a) | ((ull)f2bf(b) << 16) | ((ull)f2bf(c) << 32) |
           ((ull)f2bf(d) << 48);
}
__device__ __forceinline__ void gld16(const void* g, void* l) {
    __builtin_amdgcn_global_load_lds(
        (const __attribute__((address_space(1))) unsigned int*)g,
        (__attribute__((address_space(3))) unsigned int*)l, 16, 0, 0);
}

// prep: gather X (bf16, zero prefixes/tail, both Z buffers' prefixes),
// P1 = bf16(M), PT1 = bf16(M^T) via LDS tile transpose.
__global__ __launch_bounds__(256) void prep_kernel(
        const int* __restrict__ ids, const float* __restrict__ emb,
        const float* __restrict__ Mw, u16* __restrict__ ZA, u16* __restrict__ ZB,
        u16* __restrict__ P1, u16* __restrict__ PT1) {
    __shared__ float tile[64][65];
    const int g = blockIdx.x, tid = threadIdx.x;
    if (g < ZROWS / 16) {                         // 552 gather blocks
        for (int it = 0; it < 16; ++it) {
            const int R = g * 16 + it;
            const int b = R / ROWB, rr = R - b * ROWB;
            ull pk = 0;
            if (rr >= PREF) {
                const int t = rr - PREF;
                if (t <= SEQ) {                    // t>SEQ tail pad stays zero
                    const int id = (t == 0) ? 0 : ids[b * SEQ + t - 1];
                    const float4 v = *(const float4*)(emb + (size_t)id * DM + tid * 4);
                    pk = pack4(v.x, v.y, v.z, v.w);
                }
            } else {                               // prefix: zero BOTH buffers
                *(ull*)(ZB + (size_t)R * DM + tid * 4) = 0;
            }
            *(ull*)(ZA + (size_t)R * DM + tid * 4) = pk;
        }
    } else if (g < ZROWS / 16 + 64) {              // 64 blocks: P1 = bf16(M)
        const int i0 = (g - ZROWS / 16) * 16;
        for (int it = 0; it < 16; ++it) {
            const int i = i0 + it;
            const float4 v = *(const float4*)(Mw + (size_t)i * DM + tid * 4);
            *(ull*)(P1 + (size_t)i * DM + tid * 4) = pack4(v.x, v.y, v.z, v.w);
        }
    } else {                                       // 256 blocks: PT1 via 64x64 transpose
        const int tb = g - (ZROWS / 16 + 64);
        const int tr = tb >> 4, tc = tb & 15;
        const int ty = tid >> 4, tx = tid & 15;
#pragma unroll
        for (int it = 0; it < 4; ++it) {
            const int r = it * 16 + ty;
            const float4 v = *(const float4*)(Mw + (size_t)(tr * 64 + r) * DM + tc * 64 + tx * 4);
            tile[r][tx * 4 + 0] = v.x; tile[r][tx * 4 + 1] = v.y;
            tile[r][tx * 4 + 2] = v.z; tile[r][tx * 4 + 3] = v.w;
        }
        __syncthreads();
#pragma unroll
        for (int it = 0; it < 4; ++it) {
            const int r = it * 16 + ty;
            const ull pk = pack4(tile[tx * 4 + 0][r], tile[tx * 4 + 1][r],
                                 tile[tx * 4 + 2][r], tile[tx * 4 + 3][r]);
            *(ull*)(PT1 + (size_t)(tc * 64 + r) * DM + tr * 64 + tx * 4) = pk;
        }
    }
}

// One doubling level: Znew[t,i] = Z[t,i] + sum_k Z[t-s,k]*P_s[i,k]
// (+ piggy-backed squaring tiles: Pn = P^2, PTn = (P^2)^T, both row-major).
// GEMM form D[m,n] = sum_k A[m,k]*B[n,k]; stored rows = n (B rows), cols = m.
// 128x128 tile, BK=64, DOUBLE-BUFFERED (T3-minimum 2-phase): stage K-tile
// ks+1 into buf^1 via global_load_lds while MFMA-ing tile ks from buf;
// ONE vmcnt(0)-draining barrier per tile (vs 2 barriers + exposed latency).
// Pre-swizzled source (chunk ^= row&7) + swizzled ds_read_b128 -> ~conflict-free.
template<int POWB, bool LAST>
__global__ __launch_bounds__(256) void lvl_kernel(
        const u16* __restrict__ Zsrc, u16* __restrict__ Zdst,
        const u16* __restrict__ P, const u16* __restrict__ PT,
        u16* __restrict__ Pn, u16* __restrict__ PTn,
        float* __restrict__ out, const float* __restrict__ emb, int s) {
    __shared__ __align__(16) u16 At[2][128 * 64];   // 2 x 16 KB, chunk-swizzled
    __shared__ __align__(16) u16 Bt[2][128 * 64];   // 2 x 16 KB

    const int bid = blockIdx.x, tid = threadIdx.x;
    const int w = tid >> 6, lane = tid & 63, q = lane >> 4, li = lane & 15;
    const int mq = (w & 1) * 64, nq = (w >> 1) * 64;   // wave quadrant

    const u16 *Ab, *Bb, *biasb = nullptr;
    u16 *dstb = nullptr;
    float *outb = nullptr;
    int trow = 0, gcolb = 0;

    if (POWB && bid < POWB) {
        const int j = bid & 63, rt = j >> 3, ct = j & 7;
        if (bid < 64) {                // Pn[i][k] = sum_j PT[k,j]*P[i,j]: A=PT, B=P
            Ab = PT + (size_t)(ct * 128) * DM;
            Bb = P  + (size_t)(rt * 128) * DM;
            dstb = Pn + (size_t)(rt * 128) * DM + ct * 128;
        } else {                       // PTn[k][i]: A=P, B=PT
            Ab = P  + (size_t)(ct * 128) * DM;
            Bb = PT + (size_t)(rt * 128) * DM;
            dstb = PTn + (size_t)(rt * 128) * DM + ct * 128;
        }
    } else {
        const int lb = bid - POWB;
        // XCD grouping: bid%8 == rt%8 so the 8 col-tiles sharing a B-panel
        // land on one XCD's L2 (dispatch round-robins bid%8 across XCDs).
        int rt, ct;
        const int grp = lb >> 6;
        if (grp < 8) { rt = (lb & 7) + grp * 8; ct = (lb >> 3) & 7; }
        else         { const int r2 = lb - 512; rt = 64 + (r2 & 3); ct = r2 >> 2; }
        const int bat = rt / RTPB;
        trow  = (rt - bat * RTPB) * 128;
        gcolb = ct * 128;
        const size_t zr = (size_t)bat * ROWB + PREF + trow;
        Ab    = P + (size_t)gcolb * DM;
        Bb    = Zsrc + (zr - s) * DM;             // shift lands in zero prefix
        biasb = Zsrc + zr * DM + gcolb;
        if (!LAST) dstb = Zdst + zr * DM + gcolb;
        else       outb = out + ((size_t)bat * SOUT + trow) * DM + gcolb;
    }

    // staging: 1024 16B chunks/tile, 4 per thread; LDS linear, source pre-swizzled
    const u16* ag[4]; const u16* bg[4]; int ldst[4];
#pragma unroll
    for (int it = 0; it < 4; ++it) {
        const int G = it * 256 + tid, row = G >> 3, c = G & 7;
        const int cs = ((c ^ (row & 7)) << 3);
        ag[it]   = Ab + (size_t)row * DM + cs;
        bg[it]   = Bb + (size_t)row * DM + cs;
        ldst[it] = G * 8;
    }
    // fragment LDS byte offsets: row R, want global chunk kk*4+q -> read chunk^(R&7)
    int aoff[4][2], boff[4][2];
#pragma unroll
    for (int a = 0; a < 4; ++a) {
        const int RA = mq + a * 16 + li, RB = nq + a * 16 + li;
#pragma unroll
        for (int kk = 0; kk < 2; ++kk) {
            aoff[a][kk] = RA * 128 + ((((kk << 2) + q) ^ (RA & 7)) << 4);
            boff[a][kk] = RB * 128 + ((((kk << 2) + q) ^ (RB & 7)) << 4);
        }
    }

    f32x4 acc[4][4];
#pragma unroll
    for (int a = 0; a < 4; ++a)
#pragma unroll
        for (int c = 0; c < 4; ++c) acc[a][c] = (f32x4){0.f, 0.f, 0.f, 0.f};

    // prologue: stage tile 0 into buf 0
#pragma unroll
    for (int it = 0; it < 4; ++it) gld16(ag[it], &At[0][ldst[it]]);
#pragma unroll
    for (int it = 0; it < 4; ++it) gld16(bg[it], &Bt[0][ldst[it]]);
    asm volatile("s_waitcnt vmcnt(0)" ::: "memory");
    __syncthreads();

    int cur = 0;
    for (int ks = 0; ks < NKS; ++ks) {
        // phase 1: issue next tile's loads into the other buffer (overlaps MFMA)
        if (ks + 1 < NKS) {
            const int ko = (ks + 1) * 64;
#pragma unroll
            for (int it = 0; it < 4; ++it) gld16(ag[it] + ko, &At[cur ^ 1][ldst[it]]);
#pragma unroll
            for (int it = 0; it < 4; ++it) gld16(bg[it] + ko, &Bt[cur ^ 1][ldst[it]]);
        }
        // phase 2: compute current tile from buf[cur]
        const char* Abase = (const char*)At[cur];
        const char* Bbase = (const char*)Bt[cur];
#pragma unroll
        for (int kk = 0; kk < 2; ++kk) {
            short8 af[4], bf8[4];
#pragma unroll
            for (int a = 0; a < 4; ++a)
                af[a] = *(const short8*)(Abase + aoff[a][kk]);
#pragma unroll
            for (int c = 0; c < 4; ++c)
                bf8[c] = *(const short8*)(Bbase + boff[c][kk]);
#pragma unroll
            for (int a = 0; a < 4; ++a)
#pragma unroll
                for (int c = 0; c < 4; ++c)
                    acc[a][c] = __builtin_amdgcn_mfma_f32_16x16x32_bf16(
                        af[a], bf8[c], acc[a][c], 0, 0, 0);
        }
        // one barrier per tile: drains vmcnt (next tile landed) + lgkm (reads done)
        __syncthreads();
        cur ^= 1;
    }

    // epilogue: lane(q,li) frag (a,c) -> rows n = nq+c*16+li, cols m = mq+a*16+q*4+r
    if (POWB && bid < POWB) {
#pragma unroll
        for (int a = 0; a < 4; ++a) {
            const int mb = mq + a * 16 + q * 4;
#pragma unroll
            for (int c = 0; c < 4; ++c) {
                const int n = nq + c * 16 + li;
                *(ull*)(dstb + (size_t)n * DM + mb) =
                    pack4(acc[a][c][0], acc[a][c][1], acc[a][c][2], acc[a][c][3]);
            }
        }
    } else {
#pragma unroll
        for (int a = 0; a < 4; ++a) {
            const int mb = mq + a * 16 + q * 4;
#pragma unroll
            for (int c = 0; c < 4; ++c) {
                const int n = nq + c * 16 + li;
                const ull bz = *(const ull*)(biasb + (size_t)n * DM + mb);
                float v0 = acc[a][c][0] + bf2f((u16)bz);
                float v1 = acc[a][c][1] + bf2f((u16)(bz >> 16));
                float v2 = acc[a][c][2] + bf2f((u16)(bz >> 32));
                float v3 = acc[a][c][3] + bf2f((u16)(bz >> 48));
                if (!LAST) {
                    *(ull*)(dstb + (size_t)n * DM + mb) = pack4(v0, v1, v2, v3);
                } else {
                    const int t = trow + n;
                    if (t <= SEQ) {               // skip tail pad rows
                        if (t == 0) {             // y0 = emb[0] exact fp32
                            const float* e = emb + gcolb + mb;
                            v0 = e[0]; v1 = e[1]; v2 = e[2]; v3 = e[3];
                        }
                        *(f32x4*)(outb + (size_t)n * DM + mb) = (f32x4){v0, v1, v2, v3};
                    }
                }
            }
        }
    }
}

extern "C" void kernel_launch(void* const* d_in, const int* in_sizes, int n_in,
                              void* d_out, int out_size, void* d_ws, size_t ws_size,
                              hipStream_t stream) {
    const int*   ids = (const int*)d_in[0];
    const float* emb = (const float*)d_in[1];
    const float* Mw  = (const float*)d_in[2];
    float*       out = (float*)d_out;

    // ws: ZA 18.09 MB | Pa 2MB | PTa 2MB | Pb 2MB | PTb 2MB  = 26.5 MB
    u16* ZA  = (u16*)d_ws;
    u16* Pa  = ZA  + (size_t)ZROWS * DM;
    u16* PTa = Pa  + (size_t)DM * DM;
    u16* Pb  = PTa + (size_t)DM * DM;
    u16* PTb = Pb  + (size_t)DM * DM;
    u16* ZB  = (u16*)out;            // 18.09 MB scratch inside 33.5 MB out (dead
                                     // before the last level rewrites out in fp32)

    prep_kernel<<<dim3(872), dim3(256), 0, stream>>>(ids, emb, Mw, ZA, ZB, Pa, PTa);
    // levels: Z += shift(Z,s)·P_s ; piggy-backed P^2 (and its transpose) tiles
    lvl_kernel<128, false><<<dim3(672), dim3(256), 0, stream>>>(ZA, ZB, Pa, PTa, Pb, PTb, nullptr, emb, 1);
    lvl_kernel<128, false><<<dim3(672), dim3(256), 0, stream>>>(ZB, ZA, Pb, PTb, Pa, PTa, nullptr, emb, 2);
    lvl_kernel<128, false><<<dim3(672), dim3(256), 0, stream>>>(ZA, ZB, Pa, PTa, Pb, PTb, nullptr, emb, 4);
    lvl_kernel<64,  false><<<dim3(608), dim3(256), 0, stream>>>(ZB, ZA, Pb, PTb, Pa, PTa, nullptr, emb, 8);  // only P16 needed
    lvl_kernel<0,   true ><<<dim3(544), dim3(256), 0, stream>>>(ZA, nullptr, Pa, PTa, nullptr, nullptr, out, emb, 16);
}

// Round 3
// 475.072 us; speedup vs baseline: 1.1031x; 1.1031x over previous
//
#include <hip/hip_runtime.h>

#define DM    1024
#define NB    4
#define SEQ   2048
#define SOUT  2049
#define TPAD  2176                 // 17*128 padded t-rows per batch
#define PREF  32                   // zero prefix rows per batch (max shift 16)
#define ROWB  (PREF + TPAD)        // 2208 physical rows per batch
#define ZROWS (NB * ROWB)          // 8832
#define RTPB  (TPAD / 128)         // 17 row tiles per batch
#define NKS   (DM / 64)            // 16 K-steps of BK=64

typedef __attribute__((ext_vector_type(8)))  short short8;   // 8 x bf16
typedef __attribute__((ext_vector_type(4)))  float f32x4;
typedef __attribute__((ext_vector_type(16))) float f32x16;
typedef unsigned long long ull;
typedef unsigned short u16;

__device__ __forceinline__ u16 f2bf(float f) {
    unsigned u = __builtin_bit_cast(unsigned, f);
    u += 0x7fffu + ((u >> 16) & 1u);          // RNE
    return (u16)(u >> 16);
}
__device__ __forceinline__ float bf2f(u16 h) {
    return __builtin_bit_cast(float, (unsigned)h << 16);
}
__device__ __forceinline__ ull pack4(float a, float b, float c, float d) {
    return (ull)f2bf(a) | ((ull)f2bf(b) << 16) | ((ull)f2bf(c) << 32) |
           ((ull)f2bf(d) << 48);
}
__device__ __forceinline__ void gld16(const void* g, void* l) {
    __builtin_amdgcn_global_load_lds(
        (const __attribute__((address_space(1))) unsigned int*)g,
        (__attribute__((address_space(3))) unsigned int*)l, 16, 0, 0);
}

// prep: gather X (bf16, zero prefixes/tail, both Z buffers' prefixes),
// P1 = bf16(M), PT1 = bf16(M^T) via LDS tile transpose.
__global__ __launch_bounds__(256) void prep_kernel(
        const int* __restrict__ ids, const float* __restrict__ emb,
        const float* __restrict__ Mw, u16* __restrict__ ZA, u16* __restrict__ ZB,
        u16* __restrict__ P1, u16* __restrict__ PT1) {
    __shared__ float tile[64][65];
    const int g = blockIdx.x, tid = threadIdx.x;
    if (g < ZROWS / 16) {                         // 552 gather blocks
        for (int it = 0; it < 16; ++it) {
            const int R = g * 16 + it;
            const int b = R / ROWB, rr = R - b * ROWB;
            ull pk = 0;
            if (rr >= PREF) {
                const int t = rr - PREF;
                if (t <= SEQ) {                    // t>SEQ tail pad stays zero
                    const int id = (t == 0) ? 0 : ids[b * SEQ + t - 1];
                    const float4 v = *(const float4*)(emb + (size_t)id * DM + tid * 4);
                    pk = pack4(v.x, v.y, v.z, v.w);
                }
            } else {                               // prefix: zero BOTH buffers
                *(ull*)(ZB + (size_t)R * DM + tid * 4) = 0;
            }
            *(ull*)(ZA + (size_t)R * DM + tid * 4) = pk;
        }
    } else if (g < ZROWS / 16 + 64) {              // 64 blocks: P1 = bf16(M)
        const int i0 = (g - ZROWS / 16) * 16;
        for (int it = 0; it < 16; ++it) {
            const int i = i0 + it;
            const float4 v = *(const float4*)(Mw + (size_t)i * DM + tid * 4);
            *(ull*)(P1 + (size_t)i * DM + tid * 4) = pack4(v.x, v.y, v.z, v.w);
        }
    } else {                                       // 256 blocks: PT1 via 64x64 transpose
        const int tb = g - (ZROWS / 16 + 64);
        const int tr = tb >> 4, tc = tb & 15;
        const int ty = tid >> 4, tx = tid & 15;
#pragma unroll
        for (int it = 0; it < 4; ++it) {
            const int r = it * 16 + ty;
            const float4 v = *(const float4*)(Mw + (size_t)(tr * 64 + r) * DM + tc * 64 + tx * 4);
            tile[r][tx * 4 + 0] = v.x; tile[r][tx * 4 + 1] = v.y;
            tile[r][tx * 4 + 2] = v.z; tile[r][tx * 4 + 3] = v.w;
        }
        __syncthreads();
#pragma unroll
        for (int it = 0; it < 4; ++it) {
            const int r = it * 16 + ty;
            const ull pk = pack4(tile[tx * 4 + 0][r], tile[tx * 4 + 1][r],
                                 tile[tx * 4 + 2][r], tile[tx * 4 + 3][r]);
            *(ull*)(PT1 + (size_t)(tc * 64 + r) * DM + tr * 64 + tx * 4) = pk;
        }
    }
}

// One doubling level: Znew[t,i] = Z[t,i] + sum_k Z[t-s,k]*P_s[i,k]
// (+ piggy-backed squaring tiles: Pn = P^2, PTn = (P^2)^T, both row-major).
// GEMM form D[m,n] = sum_k A[m,k]*B[n,k]; stored rows = n (B rows), cols = m.
// 128x128 tile, BK=64, synchronous 2-barrier staging (round-1 structure:
// 32 KB LDS -> ~3 blocks/CU; cross-block overlap does the pipelining).
// Inner fragment: mfma_f32_32x32x16_bf16 (16 MFMA/K-step/wave vs 32 with
// 16x16x32; same FLOPs, +15% pipe ceiling, half the issue slots).
// Pre-swizzled source (chunk ^= row&7) + swizzled ds_read_b128 -> ~2-way max.
template<int POWB, bool LAST>
__global__ __launch_bounds__(256) void lvl_kernel(
        const u16* __restrict__ Zsrc, u16* __restrict__ Zdst,
        const u16* __restrict__ P, const u16* __restrict__ PT,
        u16* __restrict__ Pn, u16* __restrict__ PTn,
        float* __restrict__ out, const float* __restrict__ emb, int s) {
    __shared__ __align__(16) u16 At[128 * 64];   // 16 KB  [row][64k], chunk-swizzled
    __shared__ __align__(16) u16 Bt[128 * 64];   // 16 KB

    const int bid = blockIdx.x, tid = threadIdx.x;
    const int w = tid >> 6, lane = tid & 63;
    const int l31 = lane & 31, lh = lane >> 5;
    const int mq = (w & 1) * 64, nq = (w >> 1) * 64;   // wave quadrant

    const u16 *Ab, *Bb, *biasb = nullptr;
    u16 *dstb = nullptr;
    float *outb = nullptr;
    int trow = 0, gcolb = 0;

    if (POWB && bid < POWB) {
        const int j = bid & 63, rt = j >> 3, ct = j & 7;
        if (bid < 64) {                // Pn[i][k] = sum_j PT[k,j]*P[i,j]: A=PT, B=P
            Ab = PT + (size_t)(ct * 128) * DM;
            Bb = P  + (size_t)(rt * 128) * DM;
            dstb = Pn + (size_t)(rt * 128) * DM + ct * 128;
        } else {                       // PTn[k][i]: A=P, B=PT
            Ab = P  + (size_t)(ct * 128) * DM;
            Bb = PT + (size_t)(rt * 128) * DM;
            dstb = PTn + (size_t)(rt * 128) * DM + ct * 128;
        }
    } else {
        const int lb = bid - POWB;
        // XCD grouping: bid%8 == rt%8 so the 8 col-tiles sharing a B-panel
        // land on one XCD's L2 (dispatch round-robins bid%8 across XCDs).
        int rt, ct;
        const int grp = lb >> 6;
        if (grp < 8) { rt = (lb & 7) + grp * 8; ct = (lb >> 3) & 7; }
        else         { const int r2 = lb - 512; rt = 64 + (r2 & 3); ct = r2 >> 2; }
        const int bat = rt / RTPB;
        trow  = (rt - bat * RTPB) * 128;
        gcolb = ct * 128;
        const size_t zr = (size_t)bat * ROWB + PREF + trow;
        Ab    = P + (size_t)gcolb * DM;
        Bb    = Zsrc + (zr - s) * DM;             // shift lands in zero prefix
        biasb = Zsrc + zr * DM + gcolb;
        if (!LAST) dstb = Zdst + zr * DM + gcolb;
        else       outb = out + ((size_t)bat * SOUT + trow) * DM + gcolb;
    }

    // staging: 1024 16B chunks/tile, 4 per thread; LDS linear, source pre-swizzled
    const u16* ag[4]; const u16* bg[4]; u16* al[4]; u16* bl[4];
#pragma unroll
    for (int it = 0; it < 4; ++it) {
        const int G = it * 256 + tid, row = G >> 3, c = G & 7;
        const int cs = ((c ^ (row & 7)) << 3);
        ag[it] = Ab + (size_t)row * DM + cs;
        bg[it] = Bb + (size_t)row * DM + cs;
        al[it] = At + G * 8;
        bl[it] = Bt + G * 8;
    }
    // fragment LDS byte offsets for 32x32x16: lane holds [row=l&31][k=(l>>5)*8+j];
    // global chunk cg = 2*j + lh at row R -> LDS chunk cg^(R&7)
    int aoff[2][4], boff[2][4];
#pragma unroll
    for (int am = 0; am < 2; ++am) {
        const int RA = mq + am * 32 + l31, RB = nq + am * 32 + l31;
#pragma unroll
        for (int j = 0; j < 4; ++j) {
            aoff[am][j] = RA * 128 + ((((j << 1) + lh) ^ (RA & 7)) << 4);
            boff[am][j] = RB * 128 + ((((j << 1) + lh) ^ (RB & 7)) << 4);
        }
    }

    f32x16 acc[2][2];
#pragma unroll
    for (int am = 0; am < 2; ++am)
#pragma unroll
        for (int cn = 0; cn < 2; ++cn)
#pragma unroll
            for (int e = 0; e < 16; ++e) acc[am][cn][e] = 0.f;

    for (int ks = 0; ks < NKS; ++ks) {
        __syncthreads();                          // prev tile's frag reads done
        const int ko = ks * 64;
#pragma unroll
        for (int it = 0; it < 4; ++it) gld16(ag[it] + ko, al[it]);
#pragma unroll
        for (int it = 0; it < 4; ++it) gld16(bg[it] + ko, bl[it]);
        asm volatile("s_waitcnt vmcnt(0)" ::: "memory");
        __syncthreads();                          // tile visible
#pragma unroll
        for (int j = 0; j < 4; ++j) {             // 4 k-slices of 16
            short8 af[2], bf[2];
#pragma unroll
            for (int am = 0; am < 2; ++am)
                af[am] = *(const short8*)((const char*)At + aoff[am][j]);
#pragma unroll
            for (int cn = 0; cn < 2; ++cn)
                bf[cn] = *(const short8*)((const char*)Bt + boff[cn][j]);
#pragma unroll
            for (int am = 0; am < 2; ++am)
#pragma unroll
                for (int cn = 0; cn < 2; ++cn)
                    acc[am][cn] = __builtin_amdgcn_mfma_f32_32x32x16_bf16(
                        af[am], bf[cn], acc[am][cn], 0, 0, 0);
        }
    }

    // epilogue: C/D 32x32 map (m74/m101): n = l&31 (B row), m = (r&3)+8*(r>>2)+4*lh
    if (POWB && bid < POWB) {
#pragma unroll
        for (int am = 0; am < 2; ++am)
#pragma unroll
            for (int cn = 0; cn < 2; ++cn) {
                const int n = nq + cn * 32 + l31;
#pragma unroll
                for (int gg = 0; gg < 4; ++gg) {
                    const int mb = mq + am * 32 + gg * 8 + lh * 4;
                    *(ull*)(dstb + (size_t)n * DM + mb) =
                        pack4(acc[am][cn][gg * 4 + 0], acc[am][cn][gg * 4 + 1],
                              acc[am][cn][gg * 4 + 2], acc[am][cn][gg * 4 + 3]);
                }
            }
    } else {
#pragma unroll
        for (int am = 0; am < 2; ++am)
#pragma unroll
            for (int cn = 0; cn < 2; ++cn) {
                const int n = nq + cn * 32 + l31;
#pragma unroll
                for (int gg = 0; gg < 4; ++gg) {
                    const int mb = mq + am * 32 + gg * 8 + lh * 4;
                    const ull bz = *(const ull*)(biasb + (size_t)n * DM + mb);
                    float v0 = acc[am][cn][gg * 4 + 0] + bf2f((u16)bz);
                    float v1 = acc[am][cn][gg * 4 + 1] + bf2f((u16)(bz >> 16));
                    float v2 = acc[am][cn][gg * 4 + 2] + bf2f((u16)(bz >> 32));
                    float v3 = acc[am][cn][gg * 4 + 3] + bf2f((u16)(bz >> 48));
                    if (!LAST) {
                        *(ull*)(dstb + (size_t)n * DM + mb) = pack4(v0, v1, v2, v3);
                    } else {
                        const int t = trow + n;
                        if (t <= SEQ) {           // skip tail pad rows
                            if (t == 0) {         // y0 = emb[0] exact fp32
                                const float* e = emb + gcolb + mb;
                                v0 = e[0]; v1 = e[1]; v2 = e[2]; v3 = e[3];
                            }
                            *(f32x4*)(outb + (size_t)n * DM + mb) =
                                (f32x4){v0, v1, v2, v3};
                        }
                    }
                }
            }
    }
}

extern "C" void kernel_launch(void* const* d_in, const int* in_sizes, int n_in,
                              void* d_out, int out_size, void* d_ws, size_t ws_size,
                              hipStream_t stream) {
    const int*   ids = (const int*)d_in[0];
    const float* emb = (const float*)d_in[1];
    const float* Mw  = (const float*)d_in[2];
    float*       out = (float*)d_out;

    // ws: ZA 18.09 MB | Pa 2MB | PTa 2MB | Pb 2MB | PTb 2MB  = 26.5 MB
    u16* ZA  = (u16*)d_ws;
    u16* Pa  = ZA  + (size_t)ZROWS * DM;
    u16* PTa = Pa  + (size_t)DM * DM;
    u16* Pb  = PTa + (size_t)DM * DM;
    u16* PTb = Pb  + (size_t)DM * DM;
    u16* ZB  = (u16*)out;            // 18.09 MB scratch inside 33.5 MB out (dead
                                     // before the last level rewrites out in fp32)

    prep_kernel<<<dim3(872), dim3(256), 0, stream>>>(ids, emb, Mw, ZA, ZB, Pa, PTa);
    // levels: Z += shift(Z,s)·P_s ; piggy-backed P^2 (and its transpose) tiles
    lvl_kernel<128, false><<<dim3(672), dim3(256), 0, stream>>>(ZA, ZB, Pa, PTa, Pb, PTb, nullptr, emb, 1);
    lvl_kernel<128, false><<<dim3(672), dim3(256), 0, stream>>>(ZB, ZA, Pb, PTb, Pa, PTa, nullptr, emb, 2);
    lvl_kernel<128, false><<<dim3(672), dim3(256), 0, stream>>>(ZA, ZB, Pa, PTa, Pb, PTb, nullptr, emb, 4);
    lvl_kernel<64,  false><<<dim3(608), dim3(256), 0, stream>>>(ZB, ZA, Pb, PTb, Pa, PTa, nullptr, emb, 8);  // only P16 needed
    lvl_kernel<0,   true ><<<dim3(544), dim3(256), 0, stream>>>(ZA, nullptr, Pa, PTa, nullptr, nullptr, out, emb, 16);
}